// Round 1
// baseline (210.888 us; speedup 1.0000x reference)
//
#include <hip/hip_runtime.h>

// YOLO loss: pred/target (4096, 30, 14, 14) f32 -> scalar.
// S=14, B=2 boxes, C=20 classes, D=30. Memory-bound (~193 MB in, 4 B out).
// One thread handles 4 consecutive cells via float4 (196 cells = 49 quads/row).

#define S_GRID 14
#define SS 196          // S*S
#define D_CH 30
#define N_BATCH 4096
#define QPR 49          // float4 quads per (n,d) row = SS/4
#define LAMBDA_COORD 5.0f
#define LAMBDA_NOOBJ 0.5f

__global__ __launch_bounds__(256) void yolo_loss_kernel(
    const float* __restrict__ pred,
    const float* __restrict__ tgt,
    float* __restrict__ out)
{
    const int t  = blockIdx.x * 256 + threadIdx.x;   // quad index in [0, 4096*49)
    const int n  = t / QPR;
    const int qi = t - n * QPR;

    const float4* pbase = (const float4*)(pred + (size_t)n * (D_CH * SS)) + qi;
    const float4* tbase = (const float4*)(tgt  + (size_t)n * (D_CH * SS)) + qi;
    // element d of this quad: base[d * QPR]

    // Load box channels d=0..9 for pred and target (needed simultaneously for IoU)
    float P[10][4], T[10][4];
#pragma unroll
    for (int d = 0; d < 10; ++d) {
        float4 p = pbase[d * QPR];
        float4 tv = tbase[d * QPR];
        P[d][0] = p.x;  P[d][1] = p.y;  P[d][2] = p.z;  P[d][3] = p.w;
        T[d][0] = tv.x; T[d][1] = tv.y; T[d][2] = tv.z; T[d][3] = tv.w;
    }

    // Stream class channels d=10..29, accumulate per-lane squared diff
    float cls[4] = {0.f, 0.f, 0.f, 0.f};
#pragma unroll
    for (int d = 10; d < 30; ++d) {
        float4 p = pbase[d * QPR];
        float4 tv = tbase[d * QPR];
        float d0 = p.x - tv.x, d1 = p.y - tv.y, d2 = p.z - tv.z, d3 = p.w - tv.w;
        cls[0] += d0 * d0; cls[1] += d1 * d1; cls[2] += d2 * d2; cls[3] += d3 * d3;
    }

    float total = 0.f;
#pragma unroll
    for (int j = 0; j < 4; ++j) {
        const float tconf = T[4][j];
        const float obj   = (tconf > 0.f)  ? 1.f : 0.f;
        const float noobj = (tconf == 0.f) ? 1.f : 0.f;

        // no-object confidence term (both boxes' conf channels: d=4 and d=9)
        const float dc0 = P[4][j] - T[4][j];
        const float dc1 = P[9][j] - T[9][j];
        const float noobj_term = noobj * (dc0 * dc0 + dc1 * dc1);

        // target box 0 extents
        const float tcx = T[0][j] * (1.f / S_GRID);
        const float tcy = T[1][j] * (1.f / S_GRID);
        const float tltx = tcx - 0.5f * T[2][j], trbx = tcx + 0.5f * T[2][j];
        const float tlty = tcy - 0.5f * T[3][j], trby = tcy + 0.5f * T[3][j];
        const float tarea = (trbx - tltx) * (trby - tlty);

        float iou0, iou1;
#pragma unroll
        for (int b = 0; b < 2; ++b) {
            const int o = 5 * b;
            const float pcx = P[o + 0][j] * (1.f / S_GRID);
            const float pcy = P[o + 1][j] * (1.f / S_GRID);
            const float pltx = pcx - 0.5f * P[o + 2][j], prbx = pcx + 0.5f * P[o + 2][j];
            const float plty = pcy - 0.5f * P[o + 3][j], prby = pcy + 0.5f * P[o + 3][j];
            const float ltx = fmaxf(tltx, pltx), rbx = fminf(trbx, prbx);
            const float lty = fmaxf(tlty, plty), rby = fminf(trby, prby);
            const float w = fmaxf(rbx - ltx, 0.f), h = fmaxf(rby - lty, 0.f);
            const float inter = w * h;
            const float parea = (prbx - pltx) * (prby - plty);
            const float uni = tarea + parea - inter;
            const float iou = inter / ((uni == 0.f) ? 1.f : uni);
            if (b == 0) iou0 = iou; else iou1 = iou;
        }

        // argmax (first max on tie, matching jnp.argmax)
        const bool r = (iou1 > iou0);
        const float miou = fmaxf(iou0, iou1);

        const float bpr0 = r ? P[5][j] : P[0][j];
        const float bpr1 = r ? P[6][j] : P[1][j];
        const float bpr2 = r ? P[7][j] : P[2][j];
        const float bpr3 = r ? P[8][j] : P[3][j];
        const float bpr4 = r ? P[9][j] : P[4][j];
        const float btr0 = r ? T[5][j] : T[0][j];
        const float btr1 = r ? T[6][j] : T[1][j];
        const float btr2 = r ? T[7][j] : T[2][j];
        const float btr3 = r ? T[8][j] : T[3][j];

        const float dx = bpr0 - btr0, dy = bpr1 - btr1;
        const float dw = bpr2 - btr2, dh = bpr3 - btr3;
        const float dxy = dx * dx + dy * dy;
        const float dwh = dw * dw + dh * dh;
        const float dconf = bpr4 - miou;

        total += obj * (LAMBDA_COORD * (dxy + dwh) + dconf * dconf + cls[j])
               + LAMBDA_NOOBJ * noobj_term;
    }

    // wave(64) reduce
#pragma unroll
    for (int off = 32; off > 0; off >>= 1)
        total += __shfl_down(total, off);

    __shared__ float wsum[4];
    const int wid  = threadIdx.x >> 6;
    const int lane = threadIdx.x & 63;
    if (lane == 0) wsum[wid] = total;
    __syncthreads();
    if (threadIdx.x == 0) {
        float s = wsum[0] + wsum[1] + wsum[2] + wsum[3];
        atomicAdd(out, s * (1.0f / N_BATCH));
    }
}

extern "C" void kernel_launch(void* const* d_in, const int* in_sizes, int n_in,
                              void* d_out, int out_size, void* d_ws, size_t ws_size,
                              hipStream_t stream) {
    const float* pred = (const float*)d_in[0];
    const float* tgt  = (const float*)d_in[1];
    float* out = (float*)d_out;

    // d_out is re-poisoned (0xAA) before every timed replay; zero it ourselves.
    hipMemsetAsync(out, 0, sizeof(float), stream);

    const int total_quads = N_BATCH * QPR;      // 200704
    const int blocks = total_quads / 256;       // 784 exactly
    hipLaunchKernelGGL(yolo_loss_kernel, dim3(blocks), dim3(256), 0, stream,
                       pred, tgt, out);
}

// Round 2
// 207.557 us; speedup vs baseline: 1.0160x; 1.0160x over previous
//
#include <hip/hip_runtime.h>

// YOLO loss: pred/target (4096, 30, 14, 14) f32 -> scalar.
// S=14, B=2 boxes, C=20 classes, D=30. Memory-bound (~193 MB in, 4 B out).
// R2: one thread per 2 cells (float2). 196 cells = 98 pairs/row.
// 4096*98 threads = 1568 blocks x 256 -> ~24.5 waves/CU (vs 12.25 with float4)
// to cover HBM latency; R1 was latency-bound at 16% BW / 19.7% occupancy.

#define S_GRID 14
#define SS 196          // S*S
#define D_CH 30
#define N_BATCH 4096
#define PPR 98          // float2 pairs per (n,d) row = SS/2
#define LAMBDA_COORD 5.0f
#define LAMBDA_NOOBJ 0.5f

__global__ __launch_bounds__(256) void yolo_loss_kernel(
    const float* __restrict__ pred,
    const float* __restrict__ tgt,
    float* __restrict__ out)
{
    const int t  = blockIdx.x * 256 + threadIdx.x;   // pair index in [0, 4096*98)
    const int n  = t / PPR;
    const int qi = t - n * PPR;

    const float2* pbase = (const float2*)(pred + (size_t)n * (D_CH * SS)) + qi;
    const float2* tbase = (const float2*)(tgt  + (size_t)n * (D_CH * SS)) + qi;
    // element d of this pair: base[d * PPR]

    // Load box channels d=0..9 for pred and target (needed simultaneously for IoU)
    float P[10][2], T[10][2];
#pragma unroll
    for (int d = 0; d < 10; ++d) {
        float2 p  = pbase[d * PPR];
        float2 tv = tbase[d * PPR];
        P[d][0] = p.x;  P[d][1] = p.y;
        T[d][0] = tv.x; T[d][1] = tv.y;
    }

    // Stream class channels d=10..29, accumulate per-lane squared diff
    float cls[2] = {0.f, 0.f};
#pragma unroll
    for (int d = 10; d < 30; ++d) {
        float2 p  = pbase[d * PPR];
        float2 tv = tbase[d * PPR];
        float d0 = p.x - tv.x, d1 = p.y - tv.y;
        cls[0] += d0 * d0; cls[1] += d1 * d1;
    }

    float total = 0.f;
#pragma unroll
    for (int j = 0; j < 2; ++j) {
        const float tconf = T[4][j];
        const float obj   = (tconf > 0.f)  ? 1.f : 0.f;
        const float noobj = (tconf == 0.f) ? 1.f : 0.f;

        // no-object confidence term (both boxes' conf channels: d=4 and d=9)
        const float dc0 = P[4][j] - T[4][j];
        const float dc1 = P[9][j] - T[9][j];
        const float noobj_term = noobj * (dc0 * dc0 + dc1 * dc1);

        // target box 0 extents
        const float tcx = T[0][j] * (1.f / S_GRID);
        const float tcy = T[1][j] * (1.f / S_GRID);
        const float tltx = tcx - 0.5f * T[2][j], trbx = tcx + 0.5f * T[2][j];
        const float tlty = tcy - 0.5f * T[3][j], trby = tcy + 0.5f * T[3][j];
        const float tarea = (trbx - tltx) * (trby - tlty);

        float iou0, iou1;
#pragma unroll
        for (int b = 0; b < 2; ++b) {
            const int o = 5 * b;
            const float pcx = P[o + 0][j] * (1.f / S_GRID);
            const float pcy = P[o + 1][j] * (1.f / S_GRID);
            const float pltx = pcx - 0.5f * P[o + 2][j], prbx = pcx + 0.5f * P[o + 2][j];
            const float plty = pcy - 0.5f * P[o + 3][j], prby = pcy + 0.5f * P[o + 3][j];
            const float ltx = fmaxf(tltx, pltx), rbx = fminf(trbx, prbx);
            const float lty = fmaxf(tlty, plty), rby = fminf(trby, prby);
            const float w = fmaxf(rbx - ltx, 0.f), h = fmaxf(rby - lty, 0.f);
            const float inter = w * h;
            const float parea = (prbx - pltx) * (prby - plty);
            const float uni = tarea + parea - inter;
            const float iou = inter / ((uni == 0.f) ? 1.f : uni);
            if (b == 0) iou0 = iou; else iou1 = iou;
        }

        // argmax (first max on tie, matching jnp.argmax)
        const bool r = (iou1 > iou0);
        const float miou = fmaxf(iou0, iou1);

        const float bpr0 = r ? P[5][j] : P[0][j];
        const float bpr1 = r ? P[6][j] : P[1][j];
        const float bpr2 = r ? P[7][j] : P[2][j];
        const float bpr3 = r ? P[8][j] : P[3][j];
        const float bpr4 = r ? P[9][j] : P[4][j];
        const float btr0 = r ? T[5][j] : T[0][j];
        const float btr1 = r ? T[6][j] : T[1][j];
        const float btr2 = r ? T[7][j] : T[2][j];
        const float btr3 = r ? T[8][j] : T[3][j];

        const float dx = bpr0 - btr0, dy = bpr1 - btr1;
        const float dw = bpr2 - btr2, dh = bpr3 - btr3;
        const float dxy = dx * dx + dy * dy;
        const float dwh = dw * dw + dh * dh;
        const float dconf = bpr4 - miou;

        total += obj * (LAMBDA_COORD * (dxy + dwh) + dconf * dconf + cls[j])
               + LAMBDA_NOOBJ * noobj_term;
    }

    // wave(64) reduce
#pragma unroll
    for (int off = 32; off > 0; off >>= 1)
        total += __shfl_down(total, off);

    __shared__ float wsum[4];
    const int wid  = threadIdx.x >> 6;
    const int lane = threadIdx.x & 63;
    if (lane == 0) wsum[wid] = total;
    __syncthreads();
    if (threadIdx.x == 0) {
        float s = wsum[0] + wsum[1] + wsum[2] + wsum[3];
        atomicAdd(out, s * (1.0f / N_BATCH));
    }
}

extern "C" void kernel_launch(void* const* d_in, const int* in_sizes, int n_in,
                              void* d_out, int out_size, void* d_ws, size_t ws_size,
                              hipStream_t stream) {
    const float* pred = (const float*)d_in[0];
    const float* tgt  = (const float*)d_in[1];
    float* out = (float*)d_out;

    // d_out is re-poisoned (0xAA) before every timed replay; zero it ourselves.
    hipMemsetAsync(out, 0, sizeof(float), stream);

    const int total_pairs = N_BATCH * PPR;      // 401408
    const int blocks = total_pairs / 256;       // 1568 exactly
    hipLaunchKernelGGL(yolo_loss_kernel, dim3(blocks), dim3(256), 0, stream,
                       pred, tgt, out);
}